// Round 16
// baseline (6910.320 us; speedup 1.0000x reference)
//
#include <hip/hip_runtime.h>

// Text2Vec: ctx[b] = cos(ctx[b] @ emb[ids[b,s]]), s = 0..8191.
// 512 independent row-chains (8 batches x 64 rows); TWO rows per wave
// (256 waves, 1/CU): one 16 KB E-fetch feeds two chains, halving the L1/L2
// floors below the compute span. Per row per step: acc = sum_j
// readlane(v,j)*E[j][c], ascending j, single accumulator, v_fmac (== host
// fmaf chain bit-exactly); v = host_cosf(acc) (glibc replica, bit-exact R1+).
//
// Failure-isolation ledger (absmax 2.0 = regalloc copies in-flight "=v"
// load destinations when the burst->chain window has allocation pressure):
//   R8  PASS: top burst, 1 cos between burst and chain, 4 temps
//   R10-12 FAIL: 8 async defs moved mid-chain (3 different id schemes)
//   R13 PASS: R8 shape + compiler-managed SMEM id        (4034 us)
//   R14 FAIL: top burst BUT 2 f64 cos in the window + 8-temp interleave
// R15: 2 rows with the window EVACUATED -- both cos moved ABOVE the
// vmcnt(0) (they read only prev accs; eB's regs are dead there = free f64
// temp pool), sequential dual chains reusing R13's exact 4-temp chain macro.
// E loads: volatile-asm dwordx4 burst at step top ONLY. id: plain C++ SMEM
// loads. Table pre-transposed into d_ws. NO LDS.

#define BB 8
#define SS 8192
#define DD 64

typedef __attribute__((ext_vector_type(4))) float f32x4;

// ---- branchless bit-exact replica of glibc sysdeps/ieee754/flt-32 cosf ----
__device__ __forceinline__ float host_cosf(float y)
{
#pragma clang fp contract(off)
    const double hpi_inv = 0x1.45F306DC9C883p+23;  // 2/pi * 2^24
    const double hpi     = 0x1.921FB54442D18p0;    // pi/2
    const double c0 = 0x1p0;
    const double c1 = -0x1.ffffffd0c621cp-2;
    const double c2 = 0x1.55553e1068f19p-5;
    const double c3 = -0x1.6c087e89a359dp-10;
    const double c4 = 0x1.99343027bf8c3p-16;
    const double s1 = -0x1.555545995a603p-3;
    const double s2 = 0x1.1107605230bc4p-7;
    const double s3 = -0x1.994eb3774cf24p-13;

    const double x = (double)y;

    double r  = x * hpi_inv;
    int    n  = (((int)r) + 0x800000) >> 24;
    double xr = fma(-(double)n, hpi, x);

    const int  mm   = (n + 1) & 3;
    const double s  = (mm == 1 || mm == 2) ? -1.0 : 1.0;
    const bool negt = (mm & 2) != 0;

    double x2  = xr * xr;
    double x4  = x2 * x2;
    double cc2 = fma(x2, c4, c3);
    double cc1 = fma(x2, c1, c0);
    double x6  = x4 * x2;
    double cp  = fma(x4, c2, cc1);
    float fcos = (float)fma(x6, cc2, cp);
    fcos = negt ? -fcos : fcos;

    double xs  = xr * s;
    double x3  = xs * x2;
    double sp1 = fma(x2, s3, s2);
    double x7  = x3 * x2;
    double sr  = fma(x3, s1, xs);
    float fsin = (float)fma(x7, sp1, sr);

    return (n & 1) ? fsin : fcos;
}

// one-time: embT[id][(j>>2)*256 + c*4 + (j&3)] = emb[id][j*64 + c].
// Lane c's 16B chunk k = {E[4k..4k+3][c]}; wave chunk-k reads are contiguous.
__global__ void transpose_kernel(const float* __restrict__ emb,
                                 float* __restrict__ embT)
{
    const int id = blockIdx.x;
    const int t  = threadIdx.x;                 // 256 threads
    const float* src = emb + (size_t)id * (DD * DD);
    float*       dst = embT + (size_t)id * (DD * DD);
#pragma unroll
    for (int kk = 0; kk < 16; ++kk) {
        const int lin = kk * 256 + t;           // j*64 + c
        const int j = lin >> 6, c = lin & 63;
        dst[(j >> 2) * 256 + c * 4 + (j & 3)] = src[lin];
    }
}

// coalesced dwordx4: EN[h*4+k] <- embT[id] bytes [lane*16 + h*4096 + k*1024]
#define GL4(EN, H, K, OFFS) \
    asm volatile("global_load_dwordx4 %0, %1, %2 offset:" OFFS \
                 : "=v"(EN[(H)*4+(K)]) : "v"(voffE[H]), "s"(pnext))

#define GL4H(EN, H) \
    GL4(EN,H,0,"0"); GL4(EN,H,1,"1024"); GL4(EN,H,2,"2048"); GL4(EN,H,3,"3072")

// v_readlane of row-vector V into rotating SGPR temp (lane index literal)
#define RL(T, V, JL) \
    asm volatile("v_readlane_b32 %0, %1, " JL : "=s"(T) : "v"(V))
// ACC += t * e  (src0=SGPR, src1=VGPR; == fmaf(v_j, e_j, acc) bit-exactly)
#define FM(ACC, T, E) \
    asm volatile("v_fmac_f32 %0, %1, %2" : "+v"(ACC) : "s"(T), "v"(E))

// 4 j-steps (R13's proven pattern, parameterized): entry invariant t0..t2
// hold lanes 4K..4K+2; issues lanes A..D = 4K+3..4K+6 into slots (3,0,1,2).
#define G4(V, ACC, EC, K, A, B, C, D) \
    RL(t3, V, A); FM(ACC, t0, EC[K][0]); \
    RL(t0, V, B); FM(ACC, t1, EC[K][1]); \
    RL(t1, V, C); FM(ACC, t2, EC[K][2]); \
    RL(t2, V, D); FM(ACC, t3, EC[K][3]);

// full 64-j chain for one row (exactly R13's chain body)
#define CHAIN(V, ACC, EC) \
    RL(t0, V, "0"); RL(t1, V, "1"); RL(t2, V, "2"); \
    G4(V, ACC, EC, 0, "3","4","5","6")     G4(V, ACC, EC, 1, "7","8","9","10") \
    G4(V, ACC, EC, 2, "11","12","13","14") G4(V, ACC, EC, 3, "15","16","17","18") \
    G4(V, ACC, EC, 4, "19","20","21","22") G4(V, ACC, EC, 5, "23","24","25","26") \
    G4(V, ACC, EC, 6, "27","28","29","30") G4(V, ACC, EC, 7, "31","32","33","34") \
    G4(V, ACC, EC, 8, "35","36","37","38") G4(V, ACC, EC, 9, "39","40","41","42") \
    G4(V, ACC, EC,10, "43","44","45","46") G4(V, ACC, EC,11, "47","48","49","50") \
    G4(V, ACC, EC,12, "51","52","53","54") G4(V, ACC, EC,13, "55","56","57","58") \
    G4(V, ACC, EC,14, "59","60","61","62") \
    RL(t3, V, "63"); \
    FM(ACC, t0, EC[15][0]); FM(ACC, t1, EC[15][1]); \
    FM(ACC, t2, EC[15][2]); FM(ACC, t3, EC[15][3]);

// One chain step. cos of the PREVIOUS step's accs runs BEFORE the vmcnt
// (independent of the waiting loads; eB's dead regs provide the f64 temp
// pool) -- the burst->chain window then contains only the 16 load asms.
#define STEP(EC, EN, IDV, SOFF, DOCOS) do { \
    const int idf_ = bids[(s + (SOFF)) & (SS - 1)];   /* compiler s_load */ \
    if (DOCOS) { v0 = host_cosf(acc0); v1 = host_cosf(acc1); } \
    __builtin_amdgcn_sched_barrier(0);                /* cos stays above */ \
    asm volatile("s_waitcnt vmcnt(0)" ::: "memory");  /* EC E-loads ready */ \
    __builtin_amdgcn_sched_barrier(0); \
    const unsigned sid = (unsigned)__builtin_amdgcn_readfirstlane(IDV); \
    const float* pnext = embT + (size_t)sid * (DD * DD); \
    GL4H(EN, 0); GL4H(EN, 1); GL4H(EN, 2); GL4H(EN, 3); \
    __builtin_amdgcn_sched_barrier(0); \
    acc0 = 0.0f; acc1 = 0.0f; \
    CHAIN(v0, acc0, EC) \
    CHAIN(v1, acc1, EC) \
    IDV = idf_; \
} while (0)

__global__ __launch_bounds__(64, 1)
void text2vec_kernel(const int* __restrict__ ids,
                     const float* __restrict__ embT,
                     float* __restrict__ out)
{
    // blk = rp*8 + b: the 32 row-pair blocks of chain b share an XCD
    const int blk  = blockIdx.x;
    const int b    = blk & 7;
    const int rp   = blk >> 3;           // row pair 0..31
    const int r0   = rp * 2, r1 = rp * 2 + 1;
    const int lane = threadIdx.x;        // column c

    const int* bids = ids + b * SS;

    unsigned voffE[4];
#pragma unroll
    for (int h = 0; h < 4; ++h)
        voffE[h] = (unsigned)lane * 16u + (unsigned)h * 4096u;

    f32x4 eA[16], eB[16];
    float t0, t1, t2, t3;
    float acc0 = 0.0f, acc1 = 0.0f;

    // id pipeline: compiler-managed scalar loads (correct by construction)
    int idA = bids[1];                   // id for even-step prefetch (E(s+1))
    int idB = bids[2];                   // id for odd-step prefetch  (E(s+2))

    // prologue: eA <- E(ids[0]); readfirstlane guarantees SGPR for "s"(pnext)
    {
        const unsigned sid = (unsigned)__builtin_amdgcn_readfirstlane(bids[0]);
        const float* pnext = embT + (size_t)sid * (DD * DD);
        GL4H(eA, 0); GL4H(eA, 1); GL4H(eA, 2); GL4H(eA, 3);
    }

    float v0 = (lane == r0) ? 1.0f : 0.0f;  // rows r0, r1 of identity
    float v1 = (lane == r1) ? 1.0f : 0.0f;

    for (int s = 0; s < SS; s += 2) {
        // even: chains E(s) from eA; prefetch eB <- E[idA]; idA <- ids[s+3]
        STEP(eA, eB, idA, 3, (s != 0));
        // odd:  chains E(s+1) from eB; prefetch eA <- E[idB]; idB <- ids[s+4]
        STEP(eB, eA, idB, 4, true);
    }

    v0 = host_cosf(acc0);                // final step's cos
    v1 = host_cosf(acc1);
    out[b * (DD * DD) + r0 * DD + lane] = v0;
    out[b * (DD * DD) + r1 * DD + lane] = v1;
}

extern "C" void kernel_launch(void* const* d_in, const int* in_sizes, int n_in,
                              void* d_out, int out_size, void* d_ws, size_t ws_size,
                              hipStream_t stream)
{
    const int*   ids = (const int*)  d_in[0];   // [B, S] int32
    const float* emb = (const float*)d_in[1];   // [V, D*D] f32
    float*       out = (float*)      d_out;     // [B, D, D] f32
    float*       embT = (float*)     d_ws;      // V*4096 floats (1.5 MB)

    const int V = in_sizes[1] / (DD * DD);

    transpose_kernel<<<dim3(V), dim3(256), 0, stream>>>(emb, embT);
    text2vec_kernel<<<dim3(BB * DD / 2), dim3(DD), 0, stream>>>(ids, embT, out);
}

// Round 17
// 6130.804 us; speedup vs baseline: 1.1271x; 1.1271x over previous
//
#include <hip/hip_runtime.h>

// Text2Vec: ctx[b] = cos(ctx[b] @ emb[ids[b,s]]), s = 0..8191.
// 512 independent row-chains (8 batches x 64 rows); TWO rows per wave
// (256 waves, 1/CU): one 16 KB E-fetch feeds two chains (halves L1/L2
// traffic). Per row per step: acc = sum_j readlane(v,j)*E[j][c], ascending
// j, single accumulator, v_fmac (== host fmaf chain bit-exactly);
// v = host_cosf(acc) (glibc replica, bit-exact since R1).
//
// Failure-isolation ledger (absmax 2.0 = regalloc copies in-flight "=v"
// load destinations when the burst->chain window has allocation pressure):
//   R8/R13 PASS: top burst, 1 cos in window, 4 temps          (4034 us)
//   R10-12 FAIL: 8 async defs mid-chain (any id scheme)
//   R14    FAIL: interleaved dual chain + 2 f64 cos IN window
//   R15    PASS: sequential dual chain + cos ABOVE vmcnt      (6910 us,
//          hazard-stalled: 128 readlane->fmac pairs, 1 wave/CU, nothing
//          to fill ~5 wait states each)
// R16 tests the one open cell: INTERLEAVED chain + cos ABOVE vmcnt.
// Interleave stretches RL->FM distance to 14 instrs (~28 cyc, hazard dead)
// at zero extra instructions; window stays evacuated (only the 16 load
// asms between vmcnt and chain). If this fails, R14's poison was the
// 8-temp pressure and R13 is the terminal kernel.

#define BB 8
#define SS 8192
#define DD 64

typedef __attribute__((ext_vector_type(4))) float f32x4;

// ---- branchless bit-exact replica of glibc sysdeps/ieee754/flt-32 cosf ----
__device__ __forceinline__ float host_cosf(float y)
{
#pragma clang fp contract(off)
    const double hpi_inv = 0x1.45F306DC9C883p+23;  // 2/pi * 2^24
    const double hpi     = 0x1.921FB54442D18p0;    // pi/2
    const double c0 = 0x1p0;
    const double c1 = -0x1.ffffffd0c621cp-2;
    const double c2 = 0x1.55553e1068f19p-5;
    const double c3 = -0x1.6c087e89a359dp-10;
    const double c4 = 0x1.99343027bf8c3p-16;
    const double s1 = -0x1.555545995a603p-3;
    const double s2 = 0x1.1107605230bc4p-7;
    const double s3 = -0x1.994eb3774cf24p-13;

    const double x = (double)y;

    double r  = x * hpi_inv;
    int    n  = (((int)r) + 0x800000) >> 24;
    double xr = fma(-(double)n, hpi, x);

    const int  mm   = (n + 1) & 3;
    const double s  = (mm == 1 || mm == 2) ? -1.0 : 1.0;
    const bool negt = (mm & 2) != 0;

    double x2  = xr * xr;
    double x4  = x2 * x2;
    double cc2 = fma(x2, c4, c3);
    double cc1 = fma(x2, c1, c0);
    double x6  = x4 * x2;
    double cp  = fma(x4, c2, cc1);
    float fcos = (float)fma(x6, cc2, cp);
    fcos = negt ? -fcos : fcos;

    double xs  = xr * s;
    double x3  = xs * x2;
    double sp1 = fma(x2, s3, s2);
    double x7  = x3 * x2;
    double sr  = fma(x3, s1, xs);
    float fsin = (float)fma(x7, sp1, sr);

    return (n & 1) ? fsin : fcos;
}

// one-time: embT[id][(j>>2)*256 + c*4 + (j&3)] = emb[id][j*64 + c].
// Lane c's 16B chunk k = {E[4k..4k+3][c]}; wave chunk-k reads are contiguous.
__global__ void transpose_kernel(const float* __restrict__ emb,
                                 float* __restrict__ embT)
{
    const int id = blockIdx.x;
    const int t  = threadIdx.x;                 // 256 threads
    const float* src = emb + (size_t)id * (DD * DD);
    float*       dst = embT + (size_t)id * (DD * DD);
#pragma unroll
    for (int kk = 0; kk < 16; ++kk) {
        const int lin = kk * 256 + t;           // j*64 + c
        const int j = lin >> 6, c = lin & 63;
        dst[(j >> 2) * 256 + c * 4 + (j & 3)] = src[lin];
    }
}

// coalesced dwordx4: EN[h*4+k] <- embT[id] bytes [lane*16 + h*4096 + k*1024]
#define GL4(EN, H, K, OFFS) \
    asm volatile("global_load_dwordx4 %0, %1, %2 offset:" OFFS \
                 : "=v"(EN[(H)*4+(K)]) : "v"(voffE[H]), "s"(pnext))

#define GL4H(EN, H) \
    GL4(EN,H,0,"0"); GL4(EN,H,1,"1024"); GL4(EN,H,2,"2048"); GL4(EN,H,3,"3072")

// v_readlane into rotating SGPR temps; rows a/b read v0/v1
#define RLA(T, JL) \
    asm volatile("v_readlane_b32 %0, %1, " JL : "=s"(T) : "v"(v0))
#define RLB(T, JL) \
    asm volatile("v_readlane_b32 %0, %1, " JL : "=s"(T) : "v"(v1))
// acc += t * e  (src0=SGPR, src1=VGPR; == fmaf(v_j, e_j, acc) bit-exactly)
#define FM0(T, E) \
    asm volatile("v_fmac_f32 %0, %1, %2" : "+v"(acc0) : "s"(T), "v"(E))
#define FM1(T, E) \
    asm volatile("v_fmac_f32 %0, %1, %2" : "+v"(acc1) : "s"(T), "v"(E))

// 4 j-steps, both rows interleaved (R14's chain): entry invariant
// sa0..sa2/sb0..sb2 hold lanes 4K..4K+2; issues lanes A..D = 4K+3..4K+6.
// RL write->read distance 14 instrs (~28 cyc); same-acc FM spacing 8 cyc.
#define G4(EC, K, A, B, C, D) \
    RLA(sa3,A); RLB(sb3,A); FM0(sa0,EC[K][0]); FM1(sb0,EC[K][0]); \
    RLA(sa0,B); RLB(sb0,B); FM0(sa1,EC[K][1]); FM1(sb1,EC[K][1]); \
    RLA(sa1,C); RLB(sb1,C); FM0(sa2,EC[K][2]); FM1(sb2,EC[K][2]); \
    RLA(sa2,D); RLB(sb2,D); FM0(sa3,EC[K][3]); FM1(sb3,EC[K][3]);

// One chain step. cos of the PREVIOUS step's accs runs BEFORE the vmcnt
// (independent of the waiting loads; EN's dead regs provide the f64 temp
// pool) -- the burst->chain window contains only the 16 load asms (proven
// safe placement, R15).
#define STEP(EC, EN, IDV, SOFF, DOCOS) do { \
    const int idf_ = bids[(s + (SOFF)) & (SS - 1)];   /* compiler s_load */ \
    if (DOCOS) { v0 = host_cosf(acc0); v1 = host_cosf(acc1); } \
    __builtin_amdgcn_sched_barrier(0);                /* cos stays above */ \
    asm volatile("s_waitcnt vmcnt(0)" ::: "memory");  /* EC E-loads ready */ \
    __builtin_amdgcn_sched_barrier(0); \
    const unsigned sid = (unsigned)__builtin_amdgcn_readfirstlane(IDV); \
    const float* pnext = embT + (size_t)sid * (DD * DD); \
    GL4H(EN, 0); GL4H(EN, 1); GL4H(EN, 2); GL4H(EN, 3); \
    __builtin_amdgcn_sched_barrier(0); \
    acc0 = 0.0f; acc1 = 0.0f; \
    RLA(sa0,"0"); RLB(sb0,"0"); RLA(sa1,"1"); RLB(sb1,"1"); \
    RLA(sa2,"2"); RLB(sb2,"2"); \
    G4(EC, 0, "3","4","5","6")     G4(EC, 1, "7","8","9","10") \
    G4(EC, 2, "11","12","13","14") G4(EC, 3, "15","16","17","18") \
    G4(EC, 4, "19","20","21","22") G4(EC, 5, "23","24","25","26") \
    G4(EC, 6, "27","28","29","30") G4(EC, 7, "31","32","33","34") \
    G4(EC, 8, "35","36","37","38") G4(EC, 9, "39","40","41","42") \
    G4(EC,10, "43","44","45","46") G4(EC,11, "47","48","49","50") \
    G4(EC,12, "51","52","53","54") G4(EC,13, "55","56","57","58") \
    G4(EC,14, "59","60","61","62") \
    RLA(sa3,"63"); RLB(sb3,"63"); \
    FM0(sa0, EC[15][0]); FM1(sb0, EC[15][0]); \
    FM0(sa1, EC[15][1]); FM1(sb1, EC[15][1]); \
    FM0(sa2, EC[15][2]); FM1(sb2, EC[15][2]); \
    FM0(sa3, EC[15][3]); FM1(sb3, EC[15][3]); \
    IDV = idf_; \
} while (0)

__global__ __launch_bounds__(64, 1)
void text2vec_kernel(const int* __restrict__ ids,
                     const float* __restrict__ embT,
                     float* __restrict__ out)
{
    // blk = rp*8 + b: the 32 row-pair blocks of chain b share an XCD
    const int blk  = blockIdx.x;
    const int b    = blk & 7;
    const int rp   = blk >> 3;           // row pair 0..31
    const int r0   = rp * 2, r1 = rp * 2 + 1;
    const int lane = threadIdx.x;        // column c

    const int* bids = ids + b * SS;

    unsigned voffE[4];
#pragma unroll
    for (int h = 0; h < 4; ++h)
        voffE[h] = (unsigned)lane * 16u + (unsigned)h * 4096u;

    f32x4 eA[16], eB[16];
    float sa0, sa1, sa2, sa3, sb0, sb1, sb2, sb3;
    float acc0 = 0.0f, acc1 = 0.0f;

    // id pipeline: compiler-managed scalar loads (correct by construction)
    int idA = bids[1];                   // id for even-step prefetch (E(s+1))
    int idB = bids[2];                   // id for odd-step prefetch  (E(s+2))

    // prologue: eA <- E(ids[0]); readfirstlane guarantees SGPR for "s"(pnext)
    {
        const unsigned sid = (unsigned)__builtin_amdgcn_readfirstlane(bids[0]);
        const float* pnext = embT + (size_t)sid * (DD * DD);
        GL4H(eA, 0); GL4H(eA, 1); GL4H(eA, 2); GL4H(eA, 3);
    }

    float v0 = (lane == r0) ? 1.0f : 0.0f;  // rows r0, r1 of identity
    float v1 = (lane == r1) ? 1.0f : 0.0f;

    for (int s = 0; s < SS; s += 2) {
        // even: chains E(s) from eA; prefetch eB <- E[idA]; idA <- ids[s+3]
        STEP(eA, eB, idA, 3, (s != 0));
        // odd:  chains E(s+1) from eB; prefetch eA <- E[idB]; idB <- ids[s+4]
        STEP(eB, eA, idB, 4, true);
    }

    v0 = host_cosf(acc0);                // final step's cos
    v1 = host_cosf(acc1);
    out[b * (DD * DD) + r0 * DD + lane] = v0;
    out[b * (DD * DD) + r1 * DD + lane] = v1;
}

extern "C" void kernel_launch(void* const* d_in, const int* in_sizes, int n_in,
                              void* d_out, int out_size, void* d_ws, size_t ws_size,
                              hipStream_t stream)
{
    const int*   ids = (const int*)  d_in[0];   // [B, S] int32
    const float* emb = (const float*)d_in[1];   // [V, D*D] f32
    float*       out = (float*)      d_out;     // [B, D, D] f32
    float*       embT = (float*)     d_ws;      // V*4096 floats (1.5 MB)

    const int V = in_sizes[1] / (DD * DD);

    transpose_kernel<<<dim3(V), dim3(256), 0, stream>>>(emb, embT);
    text2vec_kernel<<<dim3(BB * DD / 2), dim3(DD), 0, stream>>>(ids, embT, out);
}

// Round 18
// 4027.407 us; speedup vs baseline: 1.7158x; 1.5223x over previous
//
#include <hip/hip_runtime.h>

// Text2Vec: ctx[b] = cos(ctx[b] @ emb[ids[b,s]]), s = 0..8191.
// 512 independent row-chains (8 batches x 64 rows), one wave per (b,row),
// lane c owns column c. Per step: acc = sum_j readlane(v,j)*E[j][c] with
// ascending j, single accumulator, v_fmac (== host fmaf chain bit-exactly);
// v = host_cosf(acc) (branchless glibc cosf replica, bit-exact since R1).
// Table pre-transposed once into d_ws (R8): lane c's column = 16 coalesced
// global_load_dwordx4 straight into registers; eA/eB double buffer. NO LDS.
//
// R17 ROOT CAUSE FOUND (R16 counters): VGPR_Count=72 with 128 simultaneously
// -live e-values and zero scratch traffic => the compiler was spilling the
// e-arrays to AGPRs (v_accvgpr moves, memory-free, ~256 extra VALU instrs
// per step = the 2x issue-count gap measured since R8). It also explains the
// absmax=2.0 class: an accvgpr spill-write of an in-flight "=v" load
// destination copies garbage -- placement = regalloc luck (R10-12/R14).
// FIX: amdgpu_waves_per_eu(1,2) raises the budget to 256 VGPRs/wave; ~160
// needed -> no spills, no copies, no hazard class. Structure = R13 verbatim
// (best passing kernel, 4034 us): top-of-step burst, cos in window (safe
// once nothing spills), compiler-managed SMEM id stream, 2 waves/CU.

#define BB 8
#define SS 8192
#define DD 64

typedef __attribute__((ext_vector_type(4))) float f32x4;

// ---- branchless bit-exact replica of glibc sysdeps/ieee754/flt-32 cosf ----
__device__ __forceinline__ float host_cosf(float y)
{
#pragma clang fp contract(off)
    const double hpi_inv = 0x1.45F306DC9C883p+23;  // 2/pi * 2^24
    const double hpi     = 0x1.921FB54442D18p0;    // pi/2
    const double c0 = 0x1p0;
    const double c1 = -0x1.ffffffd0c621cp-2;
    const double c2 = 0x1.55553e1068f19p-5;
    const double c3 = -0x1.6c087e89a359dp-10;
    const double c4 = 0x1.99343027bf8c3p-16;
    const double s1 = -0x1.555545995a603p-3;
    const double s2 = 0x1.1107605230bc4p-7;
    const double s3 = -0x1.994eb3774cf24p-13;

    const double x = (double)y;

    double r  = x * hpi_inv;
    int    n  = (((int)r) + 0x800000) >> 24;
    double xr = fma(-(double)n, hpi, x);

    const int  mm   = (n + 1) & 3;
    const double s  = (mm == 1 || mm == 2) ? -1.0 : 1.0;
    const bool negt = (mm & 2) != 0;

    double x2  = xr * xr;
    double x4  = x2 * x2;
    double cc2 = fma(x2, c4, c3);
    double cc1 = fma(x2, c1, c0);
    double x6  = x4 * x2;
    double cp  = fma(x4, c2, cc1);
    float fcos = (float)fma(x6, cc2, cp);
    fcos = negt ? -fcos : fcos;

    double xs  = xr * s;
    double x3  = xs * x2;
    double sp1 = fma(x2, s3, s2);
    double x7  = x3 * x2;
    double sr  = fma(x3, s1, xs);
    float fsin = (float)fma(x7, sp1, sr);

    return (n & 1) ? fsin : fcos;
}

// one-time: embT[id][(j>>2)*256 + c*4 + (j&3)] = emb[id][j*64 + c].
// Lane c's 16B chunk k = {E[4k..4k+3][c]}; wave chunk-k reads are contiguous.
__global__ void transpose_kernel(const float* __restrict__ emb,
                                 float* __restrict__ embT)
{
    const int id = blockIdx.x;
    const int t  = threadIdx.x;                 // 256 threads
    const float* src = emb + (size_t)id * (DD * DD);
    float*       dst = embT + (size_t)id * (DD * DD);
#pragma unroll
    for (int kk = 0; kk < 16; ++kk) {
        const int lin = kk * 256 + t;           // j*64 + c
        const int j = lin >> 6, c = lin & 63;
        dst[(j >> 2) * 256 + c * 4 + (j & 3)] = src[lin];
    }
}

// coalesced dwordx4: EN[h*4+k] <- embT[id] bytes [lane*16 + h*4096 + k*1024]
#define GL4(EN, H, K, OFFS) \
    asm volatile("global_load_dwordx4 %0, %1, %2 offset:" OFFS \
                 : "=v"(EN[(H)*4+(K)]) : "v"(voffE[H]), "s"(pnext))

#define GL4H(EN, H) \
    GL4(EN,H,0,"0"); GL4(EN,H,1,"1024"); GL4(EN,H,2,"2048"); GL4(EN,H,3,"3072")

// v_readlane into rotating SGPR temp (lane index literal)
#define RL(T, JL) \
    asm volatile("v_readlane_b32 %0, %1, " JL : "=s"(T) : "v"(v0))
// acc += t * e   (src0=SGPR, src1=VGPR; == fmaf(v_j, e_j, acc) bit-exactly)
#define FM(T, E) \
    asm volatile("v_fmac_f32 %0, %1, %2" : "+v"(acc) : "s"(T), "v"(E))

// 4 j-steps: consumes e[4K..4K+3] with temps t0..t3; issues readlanes 4K+3..4K+6
#define G4(EC, K, A, B, C, D) \
    RL(t3, A); FM(t0, EC[K][0]); \
    RL(t0, B); FM(t1, EC[K][1]); \
    RL(t1, C); FM(t2, EC[K][2]); \
    RL(t2, D); FM(t3, EC[K][3]);

// One chain step (R13 verbatim): ALL 16 E-loads burst at step top, then cos
// (covers the load window), then the pure-VALU chain. IDV: compiler-managed
// id (s_load, lgkm domain), refilled SOFF ahead for use next iteration.
#define STEP(EC, EN, IDV, SOFF, DOCOS) do { \
    const int idf_ = bids[(s + (SOFF)) & (SS - 1)];   /* compiler s_load */ \
    asm volatile("s_waitcnt vmcnt(0)" ::: "memory");  /* EC E-loads ready */ \
    __builtin_amdgcn_sched_barrier(0); \
    const unsigned sid = (unsigned)__builtin_amdgcn_readfirstlane(IDV); \
    const float* pnext = embT + (size_t)sid * (DD * DD); \
    GL4H(EN, 0); GL4H(EN, 1); GL4H(EN, 2); GL4H(EN, 3); \
    __builtin_amdgcn_sched_barrier(0);                /* cos stays below */ \
    if (DOCOS) v0 = host_cosf(acc); \
    acc = 0.0f; \
    RL(t0,"0"); RL(t1,"1"); RL(t2,"2"); \
    G4(EC, 0, "3","4","5","6")     G4(EC, 1, "7","8","9","10") \
    G4(EC, 2, "11","12","13","14") G4(EC, 3, "15","16","17","18") \
    G4(EC, 4, "19","20","21","22") G4(EC, 5, "23","24","25","26") \
    G4(EC, 6, "27","28","29","30") G4(EC, 7, "31","32","33","34") \
    G4(EC, 8, "35","36","37","38") G4(EC, 9, "39","40","41","42") \
    G4(EC,10, "43","44","45","46") G4(EC,11, "47","48","49","50") \
    G4(EC,12, "51","52","53","54") G4(EC,13, "55","56","57","58") \
    G4(EC,14, "59","60","61","62") \
    RL(t3,"63"); FM(t0, EC[15][0]); FM(t1, EC[15][1]); \
    FM(t2, EC[15][2]); FM(t3, EC[15][3]); \
    IDV = idf_; \
} while (0)

__global__ __attribute__((amdgpu_flat_work_group_size(64, 64),
                          amdgpu_waves_per_eu(1, 2)))
void text2vec_kernel(const int* __restrict__ ids,
                     const float* __restrict__ embT,
                     float* __restrict__ out)
{
    // blk = r*8 + b: all 64 rows of chain b share an XCD (L2-resident E)
    const int blk  = blockIdx.x;
    const int b    = blk & 7;
    const int r    = blk >> 3;           // 0..63
    const int lane = threadIdx.x;        // column c

    const int* bids = ids + b * SS;

    unsigned voffE[4];
#pragma unroll
    for (int h = 0; h < 4; ++h)
        voffE[h] = (unsigned)lane * 16u + (unsigned)h * 4096u;

    f32x4 eA[16], eB[16];
    float t0, t1, t2, t3;
    float acc = 0.0f;

    // id pipeline: all compiler-managed scalar loads (correct by construction)
    int idA = bids[1];                   // id for even-step prefetch (E(s+1))
    int idB = bids[2];                   // id for odd-step prefetch  (E(s+2))

    // prologue: eA <- E(ids[0]); readfirstlane guarantees SGPR for "s"(pnext)
    {
        const unsigned sid = (unsigned)__builtin_amdgcn_readfirstlane(bids[0]);
        const float* pnext = embT + (size_t)sid * (DD * DD);
        GL4H(eA, 0); GL4H(eA, 1); GL4H(eA, 2); GL4H(eA, 3);
    }

    float v0 = (lane == r) ? 1.0f : 0.0f;  // row r of identity

    for (int s = 0; s < SS; s += 2) {
        // even: chain E(s) from eA; prefetch eB <- E[idA]=E(s+1); idA <- ids[s+3]
        STEP(eA, eB, idA, 3, (s != 0));
        // odd:  chain E(s+1) from eB; prefetch eA <- E[idB]=E(s+2); idB <- ids[s+4]
        STEP(eB, eA, idB, 4, true);
    }

    v0 = host_cosf(acc);                 // final step's cos
    out[b * (DD * DD) + r * DD + lane] = v0;
}

extern "C" void kernel_launch(void* const* d_in, const int* in_sizes, int n_in,
                              void* d_out, int out_size, void* d_ws, size_t ws_size,
                              hipStream_t stream)
{
    const int*   ids = (const int*)  d_in[0];   // [B, S] int32
    const float* emb = (const float*)d_in[1];   // [V, D*D] f32
    float*       out = (float*)      d_out;     // [B, D, D] f32
    float*       embT = (float*)     d_ws;      // V*4096 floats (1.5 MB)

    const int V = in_sizes[1] / (DD * DD);

    transpose_kernel<<<dim3(V), dim3(256), 0, stream>>>(emb, embT);
    text2vec_kernel<<<dim3(BB * DD), dim3(DD), 0, stream>>>(ids, embT, out);
}

// Round 19
// 3708.343 us; speedup vs baseline: 1.8635x; 1.0860x over previous
//
#include <hip/hip_runtime.h>

// Text2Vec: ctx[b] = cos(ctx[b] @ emb[ids[b,s]]), s = 0..8191.
// 512 independent row-chains (8 batches x 64 rows), one wave per (b,row),
// lane c owns column c. Per step: acc = sum_j readlane(v,j)*E[j][c],
// ascending j, single accumulator, v_fmac (== host fmaf chain bit-exactly);
// v = glibc-cosf replica (bit-exact since R1), now hand-ported to f64 asm.
//
// R18: ENTIRE loop = ONE monolithic asm block. R16/R17 counters proved the
// compiler inserts ~600 cyc/step of register moves around multi-statement
// asm (e-arrays shuttling through AGPR/VGPR copies), and values living in
// hard regs ACROSS asm statements are invisible to regalloc -- C code (cos)
// between blocks may legally allocate temps into "dead" clobbered regs while
// async loads are in flight (the R10-12/R14 absmax-2.0 class). Monolith:
// zero compiler code inside => both failure modes structurally gone.
//  - E single-buffered in v[64:127]; refill load per quad issues right after
//    its last consumer (WAR-at-issue safe); counted s_waitcnt vmcnt(15) per
//    quad (FIFO: <=15 total with k new outstanding => old load k retired).
//  - id stream: in-asm s_load, pipelined 1 step (lgkm domain only).
//  - step 0 peeled in C: I@E0 row r == E0[r][:] elementwise (only +-0 can
//    differ; cos(+-0)=1.0f both) -- every asm iteration is uniform.

#define BB 8
#define SS 8192
#define DD 64

// ---- branchless bit-exact replica of glibc cosf (C version, epilogue) ----
__device__ __forceinline__ float host_cosf(float y)
{
#pragma clang fp contract(off)
    const double hpi_inv = 0x1.45F306DC9C883p+23;
    const double hpi     = 0x1.921FB54442D18p0;
    const double c0 = 0x1p0;
    const double c1 = -0x1.ffffffd0c621cp-2;
    const double c2 = 0x1.55553e1068f19p-5;
    const double c3 = -0x1.6c087e89a359dp-10;
    const double c4 = 0x1.99343027bf8c3p-16;
    const double s1 = -0x1.555545995a603p-3;
    const double s2 = 0x1.1107605230bc4p-7;
    const double s3 = -0x1.994eb3774cf24p-13;

    const double x = (double)y;
    double r  = x * hpi_inv;
    int    n  = (((int)r) + 0x800000) >> 24;
    double xr = fma(-(double)n, hpi, x);

    const int  mm   = (n + 1) & 3;
    const double s  = (mm == 1 || mm == 2) ? -1.0 : 1.0;
    const bool negt = (mm & 2) != 0;

    double x2  = xr * xr;
    double x4  = x2 * x2;
    double cc2 = fma(x2, c4, c3);
    double cc1 = fma(x2, c1, c0);
    double x6  = x4 * x2;
    double cp  = fma(x4, c2, cc1);
    float fcos = (float)fma(x6, cc2, cp);
    fcos = negt ? -fcos : fcos;

    double xs  = xr * s;
    double x3  = xs * x2;
    double sp1 = fma(x2, s3, s2);
    double x7  = x3 * x2;
    double sr  = fma(x3, s1, xs);
    float fsin = (float)fma(x7, sp1, sr);

    return (n & 1) ? fsin : fcos;
}

// one-time: embT[id][(j>>2)*256 + c*4 + (j&3)] = emb[id][j*64 + c].
__global__ void transpose_kernel(const float* __restrict__ emb,
                                 float* __restrict__ embT)
{
    const int id = blockIdx.x;
    const int t  = threadIdx.x;
    const float* src = emb + (size_t)id * (DD * DD);
    float*       dst = embT + (size_t)id * (DD * DD);
#pragma unroll
    for (int kk = 0; kk < 16; ++kk) {
        const int lin = kk * 256 + t;
        const int j = lin >> 6, c = lin & 63;
        dst[(j >> 2) * 256 + c * 4 + (j & 3)] = src[lin];
    }
}

// ---- monolith building blocks (all registers literal) ----
#define ROX(S,J)   "v_readlane_b32 s" #S ", %[vr], " #J "\n\t"
#define FRX(S,E,J) "v_fmac_f32 %[acc], s" #S ", v" #E "\n\t" \
                   "v_readlane_b32 s" #S ", %[vr], " #J "\n\t"
#define FOX(S,E)   "v_fmac_f32 %[acc], s" #S ", v" #E "\n\t"
#define WQ         "s_waitcnt vmcnt(15)\n\t"
#define LDQ(D0,D3,VO,OFF) \
    "global_load_dwordx4 v[" #D0 ":" #D3 "], " VO ", s[46:47] offset:" OFF "\n\t"

__global__ __launch_bounds__(64, 1)
void text2vec_kernel(const int* __restrict__ ids,
                     const float* __restrict__ emb,    // original layout (peel)
                     const float* __restrict__ embT,   // transposed table
                     float* __restrict__ out)
{
    const int blk  = blockIdx.x;
    const int b    = blk & 7;
    const int r    = blk >> 3;
    const int lane = threadIdx.x;

    const int* bids = ids + b * SS;
    const uintptr_t ta = (uintptr_t)embT;
    const unsigned tlo = (unsigned)ta, thi = (unsigned)(ta >> 32);
    unsigned vo0 = (unsigned)lane * 16u;
    unsigned vo1 = vo0 + 4096u, vo2 = vo0 + 8192u, vo3 = vo0 + 12288u;

    const int id0 = bids[0], id1 = bids[1], id2 = bids[2];

    // step-0 peel: acc = (I @ E(0))[r][lane] = E(0)[r][lane] (orig layout).
    // Bitwise-equal to the fmaf chain except -0 -> +0; cos maps both to 1.0f.
    float acc  = emb[(size_t)(unsigned)id0 * (DD * DD) + r * DD + lane];
    float vrow = 0.0f;

    const double d_hpinv = 0x1.45F306DC9C883p+23;
    const double d_hpi   = 0x1.921FB54442D18p0;
    const double d_c0 = 0x1p0;
    const double d_c1 = -0x1.ffffffd0c621cp-2;
    const double d_c2 = 0x1.55553e1068f19p-5;
    const double d_c3 = -0x1.6c087e89a359dp-10;
    const double d_c4 = 0x1.99343027bf8c3p-16;
    const double d_s1 = -0x1.555545995a603p-3;
    const double d_s2 = 0x1.1107605230bc4p-7;
    const double d_s3 = -0x1.994eb3774cf24p-13;

    asm volatile(
        // ---------- prologue: load E(1) into v[64:127]; init id/counter ----
        "s_lshl_b32 s44, %[id1], 14\n\t"
        "s_add_u32 s46, %[tlo], s44\n\t"
        "s_addc_u32 s47, %[thi], 0\n\t"
        LDQ(64,67,"%[vo0]","0")    LDQ(68,71,"%[vo0]","1024")
        LDQ(72,75,"%[vo0]","2048") LDQ(76,79,"%[vo0]","3072")
        LDQ(80,83,"%[vo1]","0")    LDQ(84,87,"%[vo1]","1024")
        LDQ(88,91,"%[vo1]","2048") LDQ(92,95,"%[vo1]","3072")
        LDQ(96,99,"%[vo2]","0")    LDQ(100,103,"%[vo2]","1024")
        LDQ(104,107,"%[vo2]","2048") LDQ(108,111,"%[vo2]","3072")
        LDQ(112,115,"%[vo3]","0")  LDQ(116,119,"%[vo3]","1024")
        LDQ(120,123,"%[vo3]","2048") LDQ(124,127,"%[vo3]","3072")
        "s_mov_b32 s41, %[id2]\n\t"
        "s_mov_b32 s40, 1\n\t"

        "T2V_LOOP:\n\t"
        // ---------- vrow = host_cosf(acc); acc = 0 ----------
        "v_cvt_f64_f32 v[8:9], %[acc]\n\t"            // x
        "v_mul_f64 v[10:11], v[8:9], %[hpinv]\n\t"    // r
        "v_cvt_i32_f64 v12, v[10:11]\n\t"             // (int)r (trunc)
        "v_add_u32 v12, 0x800000, v12\n\t"
        "v_ashrrev_i32 v12, 24, v12\n\t"              // n
        "v_cvt_f64_i32 v[10:11], v12\n\t"             // (double)n
        "v_fma_f64 v[8:9], -v[10:11], %[hpi], v[8:9]\n\t"  // xr
        "v_add_u32 v13, 1, v12\n\t"                   // n+1
        "v_and_b32 v14, 2, v13\n\t"
        "v_cmp_ne_u32 s[56:57], 0, v14\n\t"           // negt mask
        "v_and_b32 v14, 3, v13\n\t"                   // mm
        "v_add_u32 v14, 1, v14\n\t"
        "v_and_b32 v14, 2, v14\n\t"
        "v_cmp_ne_u32 vcc, 0, v14\n\t"                // ssel = mm in {1,2}
        "v_mov_b32 v14, 0x3ff00000\n\t"
        "v_mov_b32 v15, 0xbff00000\n\t"
        "v_cndmask_b32 v15, v14, v15, vcc\n\t"        // hi(s) = +-1.0
        "v_mov_b32 v14, 0\n\t"                        // s in v[14:15]
        "v_mul_f64 v[16:17], v[8:9], v[8:9]\n\t"      // x2
        "v_mul_f64 v[18:19], v[16:17], v[16:17]\n\t"  // x4
        "v_fma_f64 v[20:21], v[16:17], %[c4], %[c3]\n\t"   // cc2
        "v_fma_f64 v[22:23], v[16:17], %[c1], %[c0]\n\t"   // cc1
        "v_mul_f64 v[24:25], v[18:19], v[16:17]\n\t"  // x6
        "v_fma_f64 v[22:23], v[18:19], %[c2], v[22:23]\n\t" // cp
        "v_fma_f64 v[20:21], v[24:25], v[20:21], v[22:23]\n\t"
        "v_cvt_f32_f64 v26, v[20:21]\n\t"             // fcos
        "v_xor_b32 v27, 0x80000000, v26\n\t"
        "v_cndmask_b32 v26, v26, v27, s[56:57]\n\t"   // negt ? -fcos : fcos
        "v_mul_f64 v[18:19], v[8:9], v[14:15]\n\t"    // xs = xr*s
        "v_mul_f64 v[20:21], v[18:19], v[16:17]\n\t"  // x3
        "v_fma_f64 v[22:23], v[16:17], %[s3], %[s2]\n\t"   // sp1
        "v_mul_f64 v[24:25], v[20:21], v[16:17]\n\t"  // x7
        "v_fma_f64 v[18:19], v[20:21], %[s1], v[18:19]\n\t" // sr
        "v_fma_f64 v[18:19], v[24:25], v[22:23], v[18:19]\n\t"
        "v_cvt_f32_f64 v27, v[18:19]\n\t"             // fsin
        "v_and_b32 v14, 1, v12\n\t"
        "v_cmp_ne_u32 vcc, 0, v14\n\t"
        "v_cndmask_b32 %[vr], v26, v27, vcc\n\t"      // vrow
        "v_mov_b32 %[acc], 0\n\t"
        // ---------- scalar: pnext from s41; issue next id s_load ----------
        "s_waitcnt lgkmcnt(0)\n\t"
        "s_lshl_b32 s44, s41, 14\n\t"
        "s_add_u32 s46, %[tlo], s44\n\t"
        "s_addc_u32 s47, %[thi], 0\n\t"
        "s_add_u32 s43, s40, 2\n\t"
        "s_and_b32 s43, s43, 8191\n\t"
        "s_lshl_b32 s43, s43, 2\n\t"
        "s_load_dword s41, %[bids], s43\n\t"
        // ---------- chain: 64 ascending-j fmac; refill loads per quad ------
        ROX(50,0) ROX(51,1) ROX(52,2) ROX(53,3) ROX(54,4) ROX(55,5)
        WQ FRX(50,64,6)   FRX(51,65,7)   FRX(52,66,8)   FRX(53,67,9)   LDQ(64,67,"%[vo0]","0")
        WQ FRX(54,68,10)  FRX(55,69,11)  FRX(50,70,12)  FRX(51,71,13)  LDQ(68,71,"%[vo0]","1024")
        WQ FRX(52,72,14)  FRX(53,73,15)  FRX(54,74,16)  FRX(55,75,17)  LDQ(72,75,"%[vo0]","2048")
        WQ FRX(50,76,18)  FRX(51,77,19)  FRX(52,78,20)  FRX(53,79,21)  LDQ(76,79,"%[vo0]","3072")
        WQ FRX(54,80,22)  FRX(55,81,23)  FRX(50,82,24)  FRX(51,83,25)  LDQ(80,83,"%[vo1]","0")
        WQ FRX(52,84,26)  FRX(53,85,27)  FRX(54,86,28)  FRX(55,87,29)  LDQ(84,87,"%[vo1]","1024")
        WQ FRX(50,88,30)  FRX(51,89,31)  FRX(52,90,32)  FRX(53,91,33)  LDQ(88,91,"%[vo1]","2048")
        WQ FRX(54,92,34)  FRX(55,93,35)  FRX(50,94,36)  FRX(51,95,37)  LDQ(92,95,"%[vo1]","3072")
        WQ FRX(52,96,38)  FRX(53,97,39)  FRX(54,98,40)  FRX(55,99,41)  LDQ(96,99,"%[vo2]","0")
        WQ FRX(50,100,42) FRX(51,101,43) FRX(52,102,44) FRX(53,103,45) LDQ(100,103,"%[vo2]","1024")
        WQ FRX(54,104,46) FRX(55,105,47) FRX(50,106,48) FRX(51,107,49) LDQ(104,107,"%[vo2]","2048")
        WQ FRX(52,108,50) FRX(53,109,51) FRX(54,110,52) FRX(55,111,53) LDQ(108,111,"%[vo2]","3072")
        WQ FRX(50,112,54) FRX(51,113,55) FRX(52,114,56) FRX(53,115,57) LDQ(112,115,"%[vo3]","0")
        WQ FRX(54,116,58) FRX(55,117,59) FRX(50,118,60) FRX(51,119,61) LDQ(116,119,"%[vo3]","1024")
        WQ FRX(52,120,62) FRX(53,121,63) FOX(54,122)    FOX(55,123)    LDQ(120,123,"%[vo3]","2048")
        WQ FOX(50,124)    FOX(51,125)    FOX(52,126)    FOX(53,127)    LDQ(124,127,"%[vo3]","3072")
        // ---------- loop control ----------
        "s_addk_i32 s40, 1\n\t"
        "s_cmpk_lt_i32 s40, 0x2000\n\t"
        "s_cbranch_scc1 T2V_LOOP\n\t"
        "s_waitcnt vmcnt(0) lgkmcnt(0)\n\t"
        : [acc] "+v"(acc), [vr] "+v"(vrow)
        : [tlo] "s"(tlo), [thi] "s"(thi), [bids] "s"(bids),
          [vo0] "v"(vo0), [vo1] "v"(vo1), [vo2] "v"(vo2), [vo3] "v"(vo3),
          [id1] "s"(id1), [id2] "s"(id2),
          [hpinv] "s"(d_hpinv), [hpi] "s"(d_hpi), [c4] "s"(d_c4),
          [c1] "s"(d_c1), [c2] "s"(d_c2), [s1] "s"(d_s1), [s3] "s"(d_s3),
          [c3] "v"(d_c3), [c0] "v"(d_c0), [s2] "v"(d_s2)
        : "memory", "scc", "vcc",
          "s40","s41","s42","s43","s44","s45","s46","s47",
          "s50","s51","s52","s53","s54","s55","s56","s57",
          "v8","v9","v10","v11","v12","v13","v14","v15","v16","v17",
          "v18","v19","v20","v21","v22","v23","v24","v25","v26","v27",
          "v64","v65","v66","v67","v68","v69","v70","v71",
          "v72","v73","v74","v75","v76","v77","v78","v79",
          "v80","v81","v82","v83","v84","v85","v86","v87",
          "v88","v89","v90","v91","v92","v93","v94","v95",
          "v96","v97","v98","v99","v100","v101","v102","v103",
          "v104","v105","v106","v107","v108","v109","v110","v111",
          "v112","v113","v114","v115","v116","v117","v118","v119",
          "v120","v121","v122","v123","v124","v125","v126","v127");

    // final cos + store (proven C replica, bit-identical to the asm port)
    vrow = host_cosf(acc);
    out[b * (DD * DD) + r * DD + lane] = vrow;
}

extern "C" void kernel_launch(void* const* d_in, const int* in_sizes, int n_in,
                              void* d_out, int out_size, void* d_ws, size_t ws_size,
                              hipStream_t stream)
{
    const int*   ids = (const int*)  d_in[0];   // [B, S] int32
    const float* emb = (const float*)d_in[1];   // [V, D*D] f32
    float*       out = (float*)      d_out;     // [B, D, D] f32
    float*       embT = (float*)     d_ws;      // V*4096 floats (1.5 MB)

    const int V = in_sizes[1] / (DD * DD);

    transpose_kernel<<<dim3(V), dim3(256), 0, stream>>>(emb, embT);
    text2vec_kernel<<<dim3(BB * DD), dim3(DD), 0, stream>>>(ids, emb, embT, out);
}